// Round 4
// baseline (290.626 us; speedup 1.0000x reference)
//
#include <hip/hip_runtime.h>

typedef _Float16 half8 __attribute__((ext_vector_type(8)));
typedef _Float16 half4v __attribute__((ext_vector_type(4)));
typedef float floatx4 __attribute__((ext_vector_type(4)));

#define INV_TEMP 0.08838834764831845f

// ---------------- workspace layout (bytes) --------------------------------
#define OFF_WT   0                        // 3*128*1024 f16 = 786432 (swizzled)
#define OFF_QS   786432                   // qs linear [16384][128] f16, 4 MiB
#define OFF_KT   (786432 + 4194304)       // ks tiled:  [b][kt][1024 chunks]
#define OFF_VT   (OFF_KT + 4194304)       // vt tiled:  [b][kt][1024 chunks]
#define OFF_PART (OFF_VT + 4194304)       // partials: 2*8*2048*132 fp32
#define PART_BYTES (2ull * 8 * 2048 * 132 * 4)

// ---------------- weight prep (unchanged) ---------------------------------
// wt: per matrix m, 16 k-tiles of 64k; tile = 1024 chunks of 16B.
// physical chunk p = n*8 + (c ^ (n&7)), logical (n∈[0,128), c∈[0,8)).
__global__ __launch_bounds__(256) void wprep_kernel(
    const float* __restrict__ Wq, const float* __restrict__ Wk,
    const float* __restrict__ Wv, _Float16* __restrict__ wt)
{
    __shared__ _Float16 T[64 * 136];
    const int t = threadIdx.x;
    const int kt = blockIdx.x;
    const int m = blockIdx.y;
    const float* W = (m == 0) ? Wq : (m == 1) ? Wk : Wv;
    const float scale = (m == 0) ? INV_TEMP : 1.0f;
    const float* src = W + kt * 8192;

    #pragma unroll
    for (int i = 0; i < 8; i++) {
        int f = i * 1024 + t * 4;
        float4 v = *(const float4*)(src + f);
        int k = f >> 7, n = f & 127;
        _Float16* d = T + k * 136 + n;
        d[0] = (_Float16)(v.x * scale);
        d[1] = (_Float16)(v.y * scale);
        d[2] = (_Float16)(v.z * scale);
        d[3] = (_Float16)(v.w * scale);
    }
    __syncthreads();

    _Float16* dst = wt + m * 131072 + kt * 8192;
    #pragma unroll
    for (int i = 0; i < 4; i++) {
        int p = i * 256 + t;
        int n = p >> 3;
        int c = (p & 7) ^ (n & 7);
        half8 h;
        #pragma unroll
        for (int j = 0; j < 8; j++)
            h[j] = T[(c * 8 + j) * 136 + n];
        *(half8*)(dst + p * 8) = h;
    }
}

// ---------------- fused QKV projection ------------------------------------
// grid (256,3); block 256 (4 waves). 64 rows x 128 cols.
// Phase 1: stream the block's 256KB contiguous X span front-to-back
//   (1KB wave-contiguous per instruction), convert fp32->f16 in regs,
//   store the FULL 64x1024 f16 A-tile in LDS (128KB, XOR chunk swizzle).
//   This turns the K-sliced 256B/page DRAM pattern (R0-R3's 1.4TB/s cap)
//   into pure sequential streaming.
// Phase 2: 16 K-supersteps; A from LDS only; B (L2-resident wt) staged
//   via global_load_lds into a 16KB single buffer.
// LDS 144KB -> 1 block/CU; grid 768 = exactly 3 rounds/CU, no tail.
__global__ __launch_bounds__(256, 1) void proj_kernel(
    const float* __restrict__ Xq, const float* __restrict__ Xk,
    const float* __restrict__ Xv, const _Float16* __restrict__ wt,
    _Float16* __restrict__ qs, _Float16* __restrict__ ks_t,
    _Float16* __restrict__ vt_t)
{
    __shared__ _Float16 Af[64 * 1024];    // 128 KB: full A tile, f16, swizzled
    __shared__ _Float16 Bs[8192];         // 16 KB: one 64-k B tile

    const int t = threadIdx.x;
    const int lane = t & 63;
    const int w = t >> 6;
    const int quad = lane >> 4;
    const int m16 = lane & 15;
    const int yb = blockIdx.y;
    const float* X = (yb == 0) ? Xq : (yb == 1) ? Xk : Xv;
    const _Float16* W = wt + yb * 131072;
    const int m0 = blockIdx.x * 64;

    floatx4 acc[8] = {};

    // ---- phase 1: contiguous stream + convert + LDS store -----------------
    // row r, 16B-chunk ch (=k/8): physical chunk chp = (ch&~7)|((ch&7)^(r&7))
    {
        const float* src = X + (size_t)m0 * 1024;
        const int ch = t >> 1;                       // this thread's chunk/row
        const int half = (t & 1) * 4;
        #pragma unroll
        for (int g = 0; g < 8; g++) {
            float4 c0, c1, c2, c3, c4, c5, c6, c7;
            const float* s0 = src + (size_t)(g * 8) * 1024 + t * 4;
            c0 = *(const float4*)(s0);
            c1 = *(const float4*)(s0 + 1024);
            c2 = *(const float4*)(s0 + 2048);
            c3 = *(const float4*)(s0 + 3072);
            c4 = *(const float4*)(s0 + 4096);
            c5 = *(const float4*)(s0 + 5120);
            c6 = *(const float4*)(s0 + 6144);
            c7 = *(const float4*)(s0 + 7168);
            #pragma unroll
            for (int j = 0; j < 8; j++) {
                float4 c = (j == 0) ? c0 : (j == 1) ? c1 : (j == 2) ? c2 :
                           (j == 3) ? c3 : (j == 4) ? c4 : (j == 5) ? c5 :
                           (j == 6) ? c6 : c7;
                int row = g * 8 + j;
                int chp = (ch & ~7) | ((ch & 7) ^ (row & 7));
                half4v h = {(_Float16)c.x, (_Float16)c.y,
                            (_Float16)c.z, (_Float16)c.w};
                *(half4v*)(Af + row * 1024 + chp * 8 + half) = h;
            }
        }
    }
    __syncthreads();

    // ---- phase 2: K loop, B staged from L2-resident wt --------------------
    const int rm = w * 16 + m16;          // this lane's A row
    const int e = rm & 7;
    const _Float16* arow = Af + rm * 1024;

    for (int s = 0; s < 16; s++) {
        {   // stage B tile s: 1024 chunks of 16B, contiguous source
            const _Float16* src = W + s * 8192;
            #pragma unroll
            for (int i = 0; i < 4; i++) {
                int slot = (w * 4 + i) * 64 + lane;
                __builtin_amdgcn_global_load_lds(
                    (const __attribute__((address_space(1))) unsigned int*)(src + (size_t)slot * 8),
                    (__attribute__((address_space(3))) unsigned int*)(Bs + slot * 8),
                    16, 0, 0);
            }
        }
        __builtin_amdgcn_s_waitcnt(0);
        __syncthreads();

        #pragma unroll
        for (int hf2 = 0; hf2 < 2; hf2++) {
            // A fragment: k = s*64 + hf2*32 + quad*8 -> chunk s*8 + hf2*4 + quad
            int chp = s * 8 + ((hf2 * 4 + quad) ^ e);
            half8 af = *(const half8*)(arow + chp * 8);
            int sw = (hf2 * 4 + quad) ^ e;
            #pragma unroll
            for (int nt = 0; nt < 8; nt++) {
                half8 bf = *(const half8*)((const char*)Bs + (nt * 16 + m16) * 128 + sw * 16);
                acc[nt] = __builtin_amdgcn_mfma_f32_16x16x32_f16(af, bf, acc[nt], 0, 0, 0);
            }
        }
        __syncthreads();   // Bs free for next stage
    }

    const int b = m0 >> 11;
    const int kt = (m0 & 2047) >> 6;

    if (yb == 0) {
        #pragma unroll
        for (int nt = 0; nt < 8; nt++) {
            #pragma unroll
            for (int r = 0; r < 4; r++) {
                int orow = m0 + w * 16 + quad * 4 + r;
                qs[(size_t)orow * 128 + nt * 16 + m16] = (_Float16)acc[nt][r];
            }
        }
    } else if (yb == 1) {
        // ks tiled: chunk p = row*16 + (d8 ^ (row&7))
        _Float16* tile = ks_t + (size_t)(b * 32 + kt) * 8192;
        #pragma unroll
        for (int nt = 0; nt < 8; nt++) {
            #pragma unroll
            for (int r = 0; r < 4; r++) {
                int row = w * 16 + quad * 4 + r;
                int col = nt * 16 + m16;
                int p = row * 16 + ((col >> 3) ^ (row & 7));
                tile[p * 8 + (col & 7)] = (_Float16)acc[nt][r];
            }
        }
    } else {
        // vt tiled: transpose via LDS, chunk p = dv*8 + (k8 ^ (dv&7))
        _Float16* T = Af;   // 64 x 130 f16, Af is dead now
        #pragma unroll
        for (int nt = 0; nt < 8; nt++) {
            #pragma unroll
            for (int r = 0; r < 4; r++)
                T[(w * 16 + quad * 4 + r) * 130 + nt * 16 + m16] = (_Float16)acc[nt][r];
        }
        __syncthreads();
        int dv = t >> 1, hf = t & 1;
        _Float16* tile = vt_t + (size_t)(b * 32 + kt) * 8192;
        #pragma unroll
        for (int j8 = 0; j8 < 4; j8++) {
            int k8 = hf * 4 + j8;
            half8 h;
            #pragma unroll
            for (int j = 0; j < 8; j++)
                h[j] = T[(k8 * 8 + j) * 130 + dv];
            int p = dv * 8 + (k8 ^ (dv & 7));
            *(half8*)(tile + p * 8) = h;
        }
    }
}

// ---------------- flash attention -----------------------------------------
// grid (32, 8, ns); block 256. Double-buffered async K/V tiles, one barrier
// per key tile. ns==2: key-split halves write unnormalized partials + (m,l).
__global__ __launch_bounds__(256) void attn_kernel(
    const _Float16* __restrict__ qs, const _Float16* __restrict__ ks_t,
    const _Float16* __restrict__ vt_t, const int* __restrict__ mlen,
    float* __restrict__ out, float* __restrict__ part, int ns)
{
    __shared__ _Float16 kbuf[2 * 8192];     // 32 KB
    __shared__ _Float16 vbuf[2 * 8192];     // 32 KB
    __shared__ _Float16 pls[4 * 16 * 72];   // per-wave P

    const int t = threadIdx.x;
    const int lane = t & 63;
    const int w = t >> 6;
    const int quad = lane >> 4;
    const int m16 = lane & 15;
    const int b = blockIdx.y;
    const int h = blockIdx.z;
    const int q0 = blockIdx.x * 64;
    const int ml = mlen[b];
    const int nkt = (ml + 63) >> 6;
    const int hs = (nkt + ns - 1) / ns;
    const int kb0 = h * hs;
    const int kb1 = min(nkt, (h + 1) * hs);

    half8 aq[4];
    {
        const _Float16* qrow =
            qs + (size_t)(b * 2048 + q0 + w * 16 + m16) * 128 + quad * 8;
        #pragma unroll
        for (int d = 0; d < 4; d++)
            aq[d] = *(const half8*)(qrow + d * 32);
    }

    floatx4 acc[8] = {};
    float m_i[4] = {-3e38f, -3e38f, -3e38f, -3e38f};
    float l_i[4] = {0.f, 0.f, 0.f, 0.f};

    auto stage = [&](int buf, int kt) {
        const _Float16* ksrc = ks_t + (size_t)(b * 32 + kt) * 8192;
        const _Float16* vsrc = vt_t + (size_t)(b * 32 + kt) * 8192;
        #pragma unroll
        for (int i = 0; i < 4; i++) {
            int slot = (w * 4 + i) * 64 + lane;
            __builtin_amdgcn_global_load_lds(
                (const __attribute__((address_space(1))) unsigned int*)(ksrc + (size_t)slot * 8),
                (__attribute__((address_space(3))) unsigned int*)(kbuf + buf * 8192 + slot * 8),
                16, 0, 0);
            __builtin_amdgcn_global_load_lds(
                (const __attribute__((address_space(1))) unsigned int*)(vsrc + (size_t)slot * 8),
                (__attribute__((address_space(3))) unsigned int*)(vbuf + buf * 8192 + slot * 8),
                16, 0, 0);
        }
    };

    if (kb0 < kb1) {
        stage(0, kb0);
        __builtin_amdgcn_s_waitcnt(0);
        __syncthreads();

        for (int kt = kb0; kt < kb1; kt++) {
            const int cur = (kt - kb0) & 1;
            if (kt + 1 < kb1) stage(cur ^ 1, kt + 1);

            const _Float16* kb = kbuf + cur * 8192;
            const _Float16* vb = vbuf + cur * 8192;
            const int k0 = kt * 64;

            // S = (Q/temp) K^T
            floatx4 sacc[4] = {};
            #pragma unroll
            for (int d = 0; d < 4; d++) {
                #pragma unroll
                for (int nt = 0; nt < 4; nt++) {
                    int row = nt * 16 + m16;
                    int p = row * 16 + ((d * 4 + quad) ^ (row & 7));
                    half8 bf = *(const half8*)(kb + p * 8);
                    sacc[nt] = __builtin_amdgcn_mfma_f32_16x16x32_f16(aq[d], bf, sacc[nt], 0, 0, 0);
                }
            }

            // online softmax
            float p4[4][4];
            float rowmax[4], rowsum[4];
            #pragma unroll
            for (int r = 0; r < 4; r++) rowmax[r] = -3e38f;
            #pragma unroll
            for (int nt = 0; nt < 4; nt++) {
                int key = k0 + nt * 16 + m16;
                bool valid = key < ml;
                #pragma unroll
                for (int r = 0; r < 4; r++) {
                    float s = valid ? sacc[nt][r] : -3e38f;
                    p4[nt][r] = s;
                    rowmax[r] = fmaxf(rowmax[r], s);
                }
            }
            #pragma unroll
            for (int mask = 8; mask >= 1; mask >>= 1) {
                #pragma unroll
                for (int r = 0; r < 4; r++)
                    rowmax[r] = fmaxf(rowmax[r], __shfl_xor(rowmax[r], mask, 64));
            }
            #pragma unroll
            for (int r = 0; r < 4; r++) {
                float mnew = fmaxf(m_i[r], rowmax[r]);
                float alpha = __expf(m_i[r] - mnew);
                m_i[r] = mnew;
                l_i[r] *= alpha;
                #pragma unroll
                for (int nt = 0; nt < 8; nt++) acc[nt][r] *= alpha;
                rowsum[r] = 0.f;
                #pragma unroll
                for (int nt = 0; nt < 4; nt++) {
                    float ee = __expf(p4[nt][r] - mnew);
                    p4[nt][r] = ee;
                    rowsum[r] += ee;
                }
            }
            #pragma unroll
            for (int mask = 8; mask >= 1; mask >>= 1) {
                #pragma unroll
                for (int r = 0; r < 4; r++)
                    rowsum[r] += __shfl_xor(rowsum[r], mask, 64);
            }
            #pragma unroll
            for (int r = 0; r < 4; r++) l_i[r] += rowsum[r];

            // P: C-layout -> A-layout, per-wave LDS (no barrier needed)
            _Float16* pw = pls + w * 16 * 72;
            #pragma unroll
            for (int nt = 0; nt < 4; nt++) {
                #pragma unroll
                for (int r = 0; r < 4; r++)
                    pw[(quad * 4 + r) * 72 + nt * 16 + m16] = (_Float16)p4[nt][r];
            }

            // O += P @ V
            #pragma unroll
            for (int kp = 0; kp < 2; kp++) {
                half8 pa = *(const half8*)(pw + m16 * 72 + kp * 32 + quad * 8);
                #pragma unroll
                for (int nt = 0; nt < 8; nt++) {
                    int dv = nt * 16 + m16;
                    int p = dv * 8 + ((kp * 4 + quad) ^ (dv & 7));
                    half8 bf = *(const half8*)(vb + p * 8);
                    acc[nt] = __builtin_amdgcn_mfma_f32_16x16x32_f16(pa, bf, acc[nt], 0, 0, 0);
                }
            }

            __builtin_amdgcn_s_waitcnt(0);
            __syncthreads();
        }
    }

    if (ns == 1) {
        #pragma unroll
        for (int r = 0; r < 4; r++) {
            float inv_l = 1.0f / l_i[r];
            int orow = b * 2048 + q0 + w * 16 + quad * 4 + r;
            float* dst = out + (size_t)orow * 128;
            #pragma unroll
            for (int nt = 0; nt < 8; nt++)
                dst[nt * 16 + m16] = acc[nt][r] * inv_l;
        }
    } else {
        #pragma unroll
        for (int r = 0; r < 4; r++) {
            float* pr = part +
                (size_t)(h * 16384 + b * 2048 + q0 + w * 16 + quad * 4 + r) * 132;
            #pragma unroll
            for (int nt = 0; nt < 8; nt++)
                pr[nt * 16 + m16] = acc[nt][r];
            if (m16 == 0) { pr[128] = m_i[r]; pr[129] = l_i[r]; }
        }
    }
}

// ---------------- merge (ns==2 only) ---------------------------------------
__global__ __launch_bounds__(256) void merge_kernel(
    const float* __restrict__ part, float* __restrict__ out)
{
    int idx = blockIdx.x * 256 + threadIdx.x;   // 2,097,152 elements
    int row = idx >> 7, c = idx & 127;
    const float* p1 = part + (size_t)row * 132;
    const float* p2 = part + (size_t)(16384 + row) * 132;
    float m1 = p1[128], l1 = p1[129];
    float m2 = p2[128], l2 = p2[129];
    float M = fmaxf(m1, m2);
    float s1 = __expf(m1 - M), s2 = __expf(m2 - M);
    out[idx] = (p1[c] * s1 + p2[c] * s2) / (l1 * s1 + l2 * s2);
}

extern "C" void kernel_launch(void* const* d_in, const int* in_sizes, int n_in,
                              void* d_out, int out_size, void* d_ws, size_t ws_size,
                              hipStream_t stream) {
    const float* q   = (const float*)d_in[0];
    const float* k   = (const float*)d_in[1];
    const float* v   = (const float*)d_in[2];
    const int* mlen  = (const int*)d_in[3];
    const float* Wq  = (const float*)d_in[4];
    const float* Wk  = (const float*)d_in[5];
    const float* Wv  = (const float*)d_in[6];
    float* out = (float*)d_out;

    char* ws = (char*)d_ws;
    _Float16* wt   = (_Float16*)(ws + OFF_WT);
    _Float16* qs   = (_Float16*)(ws + OFF_QS);
    _Float16* ks_t = (_Float16*)(ws + OFF_KT);
    _Float16* vt_t = (_Float16*)(ws + OFF_VT);
    float* part    = (float*)(ws + OFF_PART);

    const int ns = (ws_size >= (size_t)OFF_PART + PART_BYTES) ? 2 : 1;

    hipLaunchKernelGGL(wprep_kernel, dim3(16, 3), dim3(256), 0, stream, Wq, Wk, Wv, wt);
    hipLaunchKernelGGL(proj_kernel, dim3(256, 3), dim3(256), 0, stream,
                       q, k, v, wt, qs, ks_t, vt_t);
    hipLaunchKernelGGL(attn_kernel, dim3(32, 8, ns), dim3(256), 0, stream,
                       qs, ks_t, vt_t, mlen, out, part, ns);
    if (ns == 2)
        hipLaunchKernelGGL(merge_kernel, dim3(8192), dim3(256), 0, stream, part, out);
}

// Round 5
// 267.247 us; speedup vs baseline: 1.0875x; 1.0875x over previous
//
#include <hip/hip_runtime.h>

typedef _Float16 half8 __attribute__((ext_vector_type(8)));
typedef float floatx4 __attribute__((ext_vector_type(4)));

#define INV_TEMP 0.08838834764831845f

// ---------------- workspace layout (bytes) --------------------------------
#define OFF_WT   0                        // 3*128*1024 f16 = 786432 (swizzled)
#define OFF_QS   786432                   // qs linear [16384][128] f16, 4 MiB
#define OFF_KT   (786432 + 4194304)       // ks tiled:  [b][kt][1024 chunks]
#define OFF_VT   (OFF_KT + 4194304)       // vt tiled:  [b][kt][1024 chunks]
#define OFF_PART (OFF_VT + 4194304)       // partials: 2*8*2048*132 fp32
#define PART_BYTES (2ull * 8 * 2048 * 132 * 4)

// ---------------- weight prep (unchanged) ---------------------------------
// wt: per matrix m, 16 k-tiles of 64k; tile = 1024 chunks of 16B.
// physical chunk p = n*8 + (c ^ (n&7)), logical (n∈[0,128), c∈[0,8)).
__global__ __launch_bounds__(256) void wprep_kernel(
    const float* __restrict__ Wq, const float* __restrict__ Wk,
    const float* __restrict__ Wv, _Float16* __restrict__ wt)
{
    __shared__ _Float16 T[64 * 136];
    const int t = threadIdx.x;
    const int kt = blockIdx.x;
    const int m = blockIdx.y;
    const float* W = (m == 0) ? Wq : (m == 1) ? Wk : Wv;
    const float scale = (m == 0) ? INV_TEMP : 1.0f;
    const float* src = W + kt * 8192;

    #pragma unroll
    for (int i = 0; i < 8; i++) {
        int f = i * 1024 + t * 4;
        float4 v = *(const float4*)(src + f);
        int k = f >> 7, n = f & 127;
        _Float16* d = T + k * 136 + n;
        d[0] = (_Float16)(v.x * scale);
        d[1] = (_Float16)(v.y * scale);
        d[2] = (_Float16)(v.z * scale);
        d[3] = (_Float16)(v.w * scale);
    }
    __syncthreads();

    _Float16* dst = wt + m * 131072 + kt * 8192;
    #pragma unroll
    for (int i = 0; i < 4; i++) {
        int p = i * 256 + t;
        int n = p >> 3;
        int c = (p & 7) ^ (n & 7);
        half8 h;
        #pragma unroll
        for (int j = 0; j < 8; j++)
            h[j] = T[(c * 8 + j) * 136 + n];
        *(half8*)(dst + p * 8) = h;
    }
}

// ---------------- fused QKV projection ------------------------------------
// grid (128,3); block 256 (4 waves). TILE_M=128 rows x 128 cols, BK=64,
// 16 supersteps. Rationale (R4 post-mortem): proj is VMEM-byte bound
// (~400MB through the per-CU vector-memory pipe at ~78% of the m13 ceiling).
// Doubling TILE_M halves the wt reread (196MB -> 98MB), total ~302MB.
// LDS = A 128x64 fp32 (32KB, single) + B 2x16KB dbuf = 64KB -> 2 blocks/CU
// (two barrier domains per CU -- the thing R0 had and R4 lost).
// B(s+1) is issued before compute(s), so the per-superstep vmcnt(0) drain
// (inside __syncthreads) effectively waits only on A's tail.
__global__ __launch_bounds__(256, 2) void proj_kernel(
    const float* __restrict__ Xq, const float* __restrict__ Xk,
    const float* __restrict__ Xv, const _Float16* __restrict__ wt,
    _Float16* __restrict__ qs, _Float16* __restrict__ ks_t,
    _Float16* __restrict__ vt_t)
{
    __shared__ char smem[65536];
    float* As = (float*)smem;                       // 128 x 64 fp32 = 32 KB
    _Float16* Bs0 = (_Float16*)(smem + 32768);      // 16 KB
    _Float16* Bs1 = (_Float16*)(smem + 49152);      // 16 KB

    const int t = threadIdx.x;
    const int lane = t & 63;
    const int w = t >> 6;
    const int quad = lane >> 4;
    const int m16 = lane & 15;
    const int yb = blockIdx.y;
    const float* X = (yb == 0) ? Xq : (yb == 1) ? Xk : Xv;
    const _Float16* W = wt + yb * 131072;
    const int m0 = blockIdx.x * 128;

    floatx4 acc[2][8] = {};
    const int e = m16 & 7;

    const float* Xbase = X + (size_t)m0 * 1024;

#define STAGEA(s)                                                             \
    {                                                                         \
        _Pragma("unroll")                                                     \
        for (int _i = 0; _i < 8; _i++) {                                      \
            int _st = _i * 256 + t;                                           \
            int _row = _st >> 4;                                              \
            int _p = _st & 15;                                                \
            int _c = (_p & 8) | ((_p & 7) ^ (_row & 7));                      \
            __builtin_amdgcn_global_load_lds(                                 \
                (const __attribute__((address_space(1))) unsigned int*)(Xbase + (size_t)_row * 1024 + (s) * 64 + _c * 4), \
                (__attribute__((address_space(3))) unsigned int*)(As + _st * 4), \
                16, 0, 0);                                                    \
        }                                                                     \
    }

#define STAGEB(dst, s)                                                        \
    {                                                                         \
        const _Float16* _src = W + (s) * 8192;                                \
        _Pragma("unroll")                                                     \
        for (int _i = 0; _i < 4; _i++) {                                      \
            int _slot = (w * 4 + _i) * 64 + lane;                             \
            __builtin_amdgcn_global_load_lds(                                 \
                (const __attribute__((address_space(1))) unsigned int*)(_src + (size_t)_slot * 8), \
                (__attribute__((address_space(3))) unsigned int*)((dst) + _slot * 8), \
                16, 0, 0);                                                    \
        }                                                                     \
    }

    STAGEA(0);
    STAGEB(Bs0, 0);

    for (int s = 0; s < 16; s++) {
        __syncthreads();   // emits s_waitcnt vmcnt(0) lgkmcnt(0) + s_barrier:
                           // A(s) and B(s) landed in LDS, visible to all waves.

        const _Float16* bcur = (s & 1) ? Bs1 : Bs0;
        if (s + 1 < 16) {
            // B(s+1) prefetch: in flight through compute(s) + barrier +
            // stageA(s+1); only drained at the NEXT top-sync.
            if (s & 1) { STAGEB(Bs0, s + 1); } else { STAGEB(Bs1, s + 1); }
        }

        // compute superstep s: 32 MFMA, B-fragments reused across mt
        #pragma unroll
        for (int hf2 = 0; hf2 < 2; hf2++) {
            half8 af0, af1;
            #pragma unroll
            for (int mt = 0; mt < 2; mt++) {
                int rm = w * 32 + mt * 16 + m16;
                const float* ap = As + rm * 64;
                float4 fa = *(const float4*)(ap + (hf2 * 8 + ((quad * 2) ^ e)) * 4);
                float4 fb = *(const float4*)(ap + (hf2 * 8 + ((quad * 2 + 1) ^ e)) * 4);
                half8 af = {(_Float16)fa.x, (_Float16)fa.y, (_Float16)fa.z, (_Float16)fa.w,
                            (_Float16)fb.x, (_Float16)fb.y, (_Float16)fb.z, (_Float16)fb.w};
                if (mt == 0) af0 = af; else af1 = af;
            }
            int sw = (hf2 * 4 + quad) ^ e;
            #pragma unroll
            for (int nt = 0; nt < 8; nt++) {
                half8 bf = *(const half8*)((const char*)bcur + (nt * 16 + m16) * 128 + sw * 16);
                acc[0][nt] = __builtin_amdgcn_mfma_f32_16x16x32_f16(af0, bf, acc[0][nt], 0, 0, 0);
                acc[1][nt] = __builtin_amdgcn_mfma_f32_16x16x32_f16(af1, bf, acc[1][nt], 0, 0, 0);
            }
        }

        // readers done with As / Bs[cur] (LDS reads tracked by lgkmcnt) --
        // raw barrier WITHOUT vmcnt drain so B(s+1) stays in flight.
        asm volatile("s_waitcnt lgkmcnt(0)" ::: "memory");
        __builtin_amdgcn_s_barrier();
        asm volatile("" ::: "memory");

        if (s + 1 < 16) STAGEA(s + 1);
    }

#undef STAGEA
#undef STAGEB

    const int b = m0 >> 11;
    const int kt0 = (m0 & 2047) >> 6;

    if (yb == 0) {
        #pragma unroll
        for (int mt = 0; mt < 2; mt++) {
            #pragma unroll
            for (int nt = 0; nt < 8; nt++) {
                #pragma unroll
                for (int r = 0; r < 4; r++) {
                    int orow = m0 + w * 32 + mt * 16 + quad * 4 + r;
                    qs[(size_t)orow * 128 + nt * 16 + m16] = (_Float16)acc[mt][nt][r];
                }
            }
        }
    } else if (yb == 1) {
        // ks tiled: chunk p = row*16 + (d8 ^ (row&7)), per 64-row key tile
        #pragma unroll
        for (int mt = 0; mt < 2; mt++) {
            #pragma unroll
            for (int nt = 0; nt < 8; nt++) {
                #pragma unroll
                for (int r = 0; r < 4; r++) {
                    int rb = w * 32 + mt * 16 + quad * 4 + r;
                    int kt = kt0 + (rb >> 6);
                    int row = rb & 63;
                    int col = nt * 16 + m16;
                    _Float16* tile = ks_t + (size_t)(b * 32 + kt) * 8192;
                    int p = row * 16 + ((col >> 3) ^ (row & 7));
                    tile[p * 8 + (col & 7)] = (_Float16)acc[mt][nt][r];
                }
            }
        }
    } else {
        // vt tiled: transpose via LDS, chunk p = dv*8 + (k8 ^ (dv&7))
        _Float16* T = (_Float16*)smem;   // 128 x 130 f16 = 33.3 KB < 64 KB
        #pragma unroll
        for (int mt = 0; mt < 2; mt++) {
            #pragma unroll
            for (int nt = 0; nt < 8; nt++) {
                #pragma unroll
                for (int r = 0; r < 4; r++) {
                    int rb = w * 32 + mt * 16 + quad * 4 + r;
                    T[rb * 130 + nt * 16 + m16] = (_Float16)acc[mt][nt][r];
                }
            }
        }
        __syncthreads();
        int dv = t >> 1, hf = t & 1;
        #pragma unroll
        for (int tile_i = 0; tile_i < 2; tile_i++) {
            _Float16* tile = vt_t + (size_t)(b * 32 + kt0 + tile_i) * 8192;
            #pragma unroll
            for (int j8 = 0; j8 < 4; j8++) {
                int k8 = hf * 4 + j8;
                half8 h;
                #pragma unroll
                for (int j = 0; j < 8; j++)
                    h[j] = T[(tile_i * 64 + k8 * 8 + j) * 130 + dv];
                int p = dv * 8 + (k8 ^ (dv & 7));
                *(half8*)(tile + p * 8) = h;
            }
        }
    }
}

// ---------------- flash attention -----------------------------------------
// grid (32, 8, ns); block 256. Double-buffered async K/V tiles, one barrier
// per key tile. ns==2: key-split halves write unnormalized partials + (m,l).
__global__ __launch_bounds__(256) void attn_kernel(
    const _Float16* __restrict__ qs, const _Float16* __restrict__ ks_t,
    const _Float16* __restrict__ vt_t, const int* __restrict__ mlen,
    float* __restrict__ out, float* __restrict__ part, int ns)
{
    __shared__ _Float16 kbuf[2 * 8192];     // 32 KB
    __shared__ _Float16 vbuf[2 * 8192];     // 32 KB
    __shared__ _Float16 pls[4 * 16 * 72];   // per-wave P

    const int t = threadIdx.x;
    const int lane = t & 63;
    const int w = t >> 6;
    const int quad = lane >> 4;
    const int m16 = lane & 15;
    const int b = blockIdx.y;
    const int h = blockIdx.z;
    const int q0 = blockIdx.x * 64;
    const int ml = mlen[b];
    const int nkt = (ml + 63) >> 6;
    const int hs = (nkt + ns - 1) / ns;
    const int kb0 = h * hs;
    const int kb1 = min(nkt, (h + 1) * hs);

    half8 aq[4];
    {
        const _Float16* qrow =
            qs + (size_t)(b * 2048 + q0 + w * 16 + m16) * 128 + quad * 8;
        #pragma unroll
        for (int d = 0; d < 4; d++)
            aq[d] = *(const half8*)(qrow + d * 32);
    }

    floatx4 acc[8] = {};
    float m_i[4] = {-3e38f, -3e38f, -3e38f, -3e38f};
    float l_i[4] = {0.f, 0.f, 0.f, 0.f};

    auto stage = [&](int buf, int kt) {
        const _Float16* ksrc = ks_t + (size_t)(b * 32 + kt) * 8192;
        const _Float16* vsrc = vt_t + (size_t)(b * 32 + kt) * 8192;
        #pragma unroll
        for (int i = 0; i < 4; i++) {
            int slot = (w * 4 + i) * 64 + lane;
            __builtin_amdgcn_global_load_lds(
                (const __attribute__((address_space(1))) unsigned int*)(ksrc + (size_t)slot * 8),
                (__attribute__((address_space(3))) unsigned int*)(kbuf + buf * 8192 + slot * 8),
                16, 0, 0);
            __builtin_amdgcn_global_load_lds(
                (const __attribute__((address_space(1))) unsigned int*)(vsrc + (size_t)slot * 8),
                (__attribute__((address_space(3))) unsigned int*)(vbuf + buf * 8192 + slot * 8),
                16, 0, 0);
        }
    };

    if (kb0 < kb1) {
        stage(0, kb0);
        __builtin_amdgcn_s_waitcnt(0);
        __syncthreads();

        for (int kt = kb0; kt < kb1; kt++) {
            const int cur = (kt - kb0) & 1;
            if (kt + 1 < kb1) stage(cur ^ 1, kt + 1);

            const _Float16* kb = kbuf + cur * 8192;
            const _Float16* vb = vbuf + cur * 8192;
            const int k0 = kt * 64;

            // S = (Q/temp) K^T
            floatx4 sacc[4] = {};
            #pragma unroll
            for (int d = 0; d < 4; d++) {
                #pragma unroll
                for (int nt = 0; nt < 4; nt++) {
                    int row = nt * 16 + m16;
                    int p = row * 16 + ((d * 4 + quad) ^ (row & 7));
                    half8 bf = *(const half8*)(kb + p * 8);
                    sacc[nt] = __builtin_amdgcn_mfma_f32_16x16x32_f16(aq[d], bf, sacc[nt], 0, 0, 0);
                }
            }

            // online softmax
            float p4[4][4];
            float rowmax[4], rowsum[4];
            #pragma unroll
            for (int r = 0; r < 4; r++) rowmax[r] = -3e38f;
            #pragma unroll
            for (int nt = 0; nt < 4; nt++) {
                int key = k0 + nt * 16 + m16;
                bool valid = key < ml;
                #pragma unroll
                for (int r = 0; r < 4; r++) {
                    float s = valid ? sacc[nt][r] : -3e38f;
                    p4[nt][r] = s;
                    rowmax[r] = fmaxf(rowmax[r], s);
                }
            }
            #pragma unroll
            for (int mask = 8; mask >= 1; mask >>= 1) {
                #pragma unroll
                for (int r = 0; r < 4; r++)
                    rowmax[r] = fmaxf(rowmax[r], __shfl_xor(rowmax[r], mask, 64));
            }
            #pragma unroll
            for (int r = 0; r < 4; r++) {
                float mnew = fmaxf(m_i[r], rowmax[r]);
                float alpha = __expf(m_i[r] - mnew);
                m_i[r] = mnew;
                l_i[r] *= alpha;
                #pragma unroll
                for (int nt = 0; nt < 8; nt++) acc[nt][r] *= alpha;
                rowsum[r] = 0.f;
                #pragma unroll
                for (int nt = 0; nt < 4; nt++) {
                    float ee = __expf(p4[nt][r] - mnew);
                    p4[nt][r] = ee;
                    rowsum[r] += ee;
                }
            }
            #pragma unroll
            for (int mask = 8; mask >= 1; mask >>= 1) {
                #pragma unroll
                for (int r = 0; r < 4; r++)
                    rowsum[r] += __shfl_xor(rowsum[r], mask, 64);
            }
            #pragma unroll
            for (int r = 0; r < 4; r++) l_i[r] += rowsum[r];

            // P: C-layout -> A-layout, per-wave LDS (no barrier needed)
            _Float16* pw = pls + w * 16 * 72;
            #pragma unroll
            for (int nt = 0; nt < 4; nt++) {
                #pragma unroll
                for (int r = 0; r < 4; r++)
                    pw[(quad * 4 + r) * 72 + nt * 16 + m16] = (_Float16)p4[nt][r];
            }

            // O += P @ V
            #pragma unroll
            for (int kp = 0; kp < 2; kp++) {
                half8 pa = *(const half8*)(pw + m16 * 72 + kp * 32 + quad * 8);
                #pragma unroll
                for (int nt = 0; nt < 8; nt++) {
                    int dv = nt * 16 + m16;
                    int p = dv * 8 + ((kp * 4 + quad) ^ (dv & 7));
                    half8 bf = *(const half8*)(vb + p * 8);
                    acc[nt] = __builtin_amdgcn_mfma_f32_16x16x32_f16(pa, bf, acc[nt], 0, 0, 0);
                }
            }

            __builtin_amdgcn_s_waitcnt(0);
            __syncthreads();
        }
    }

    if (ns == 1) {
        #pragma unroll
        for (int r = 0; r < 4; r++) {
            float inv_l = 1.0f / l_i[r];
            int orow = b * 2048 + q0 + w * 16 + quad * 4 + r;
            float* dst = out + (size_t)orow * 128;
            #pragma unroll
            for (int nt = 0; nt < 8; nt++)
                dst[nt * 16 + m16] = acc[nt][r] * inv_l;
        }
    } else {
        #pragma unroll
        for (int r = 0; r < 4; r++) {
            float* pr = part +
                (size_t)(h * 16384 + b * 2048 + q0 + w * 16 + quad * 4 + r) * 132;
            #pragma unroll
            for (int nt = 0; nt < 8; nt++)
                pr[nt * 16 + m16] = acc[nt][r];
            if (m16 == 0) { pr[128] = m_i[r]; pr[129] = l_i[r]; }
        }
    }
}

// ---------------- merge (ns==2 only) ---------------------------------------
__global__ __launch_bounds__(256) void merge_kernel(
    const float* __restrict__ part, float* __restrict__ out)
{
    int idx = blockIdx.x * 256 + threadIdx.x;   // 2,097,152 elements
    int row = idx >> 7, c = idx & 127;
    const float* p1 = part + (size_t)row * 132;
    const float* p2 = part + (size_t)(16384 + row) * 132;
    float m1 = p1[128], l1 = p1[129];
    float m2 = p2[128], l2 = p2[129];
    float M = fmaxf(m1, m2);
    float s1 = __expf(m1 - M), s2 = __expf(m2 - M);
    out[idx] = (p1[c] * s1 + p2[c] * s2) / (l1 * s1 + l2 * s2);
}

extern "C" void kernel_launch(void* const* d_in, const int* in_sizes, int n_in,
                              void* d_out, int out_size, void* d_ws, size_t ws_size,
                              hipStream_t stream) {
    const float* q   = (const float*)d_in[0];
    const float* k   = (const float*)d_in[1];
    const float* v   = (const float*)d_in[2];
    const int* mlen  = (const int*)d_in[3];
    const float* Wq  = (const float*)d_in[4];
    const float* Wk  = (const float*)d_in[5];
    const float* Wv  = (const float*)d_in[6];
    float* out = (float*)d_out;

    char* ws = (char*)d_ws;
    _Float16* wt   = (_Float16*)(ws + OFF_WT);
    _Float16* qs   = (_Float16*)(ws + OFF_QS);
    _Float16* ks_t = (_Float16*)(ws + OFF_KT);
    _Float16* vt_t = (_Float16*)(ws + OFF_VT);
    float* part    = (float*)(ws + OFF_PART);

    const int ns = (ws_size >= (size_t)OFF_PART + PART_BYTES) ? 2 : 1;

    hipLaunchKernelGGL(wprep_kernel, dim3(16, 3), dim3(256), 0, stream, Wq, Wk, Wv, wt);
    hipLaunchKernelGGL(proj_kernel, dim3(128, 3), dim3(256), 0, stream,
                       q, k, v, wt, qs, ks_t, vt_t);
    hipLaunchKernelGGL(attn_kernel, dim3(32, 8, ns), dim3(256), 0, stream,
                       qs, ks_t, vt_t, mlen, out, part, ns);
    if (ns == 2)
        hipLaunchKernelGGL(merge_kernel, dim3(8192), dim3(256), 0, stream, part, out);
}

// Round 7
// 262.207 us; speedup vs baseline: 1.1084x; 1.0192x over previous
//
#include <hip/hip_runtime.h>

typedef _Float16 half8 __attribute__((ext_vector_type(8)));
typedef float floatx4 __attribute__((ext_vector_type(4)));

#define INV_TEMP 0.08838834764831845f

// ---------------- workspace layout (bytes) --------------------------------
#define OFF_WT   0                        // 3*128*1024 f16 = 786432 (swizzled)
#define OFF_QS   786432                   // qs linear [16384][128] f16, 4 MiB
#define OFF_KT   (786432 + 4194304)       // ks tiled:  [b][kt][1024 chunks]
#define OFF_VT   (OFF_KT + 4194304)       // vt tiled:  [b][kt][1024 chunks]
#define OFF_PART (OFF_VT + 4194304)       // partials: 2*8*2048*132 fp32
#define PART_BYTES (2ull * 8 * 2048 * 132 * 4)

// ---------------- weight prep (unchanged) ---------------------------------
// wt: per matrix m, 16 k-tiles of 64k; tile = 1024 chunks of 16B.
// physical chunk p = n*8 + (c ^ (n&7)), logical (n∈[0,128), c∈[0,8)).
__global__ __launch_bounds__(256) void wprep_kernel(
    const float* __restrict__ Wq, const float* __restrict__ Wk,
    const float* __restrict__ Wv, _Float16* __restrict__ wt)
{
    __shared__ _Float16 T[64 * 136];
    const int t = threadIdx.x;
    const int kt = blockIdx.x;
    const int m = blockIdx.y;
    const float* W = (m == 0) ? Wq : (m == 1) ? Wk : Wv;
    const float scale = (m == 0) ? INV_TEMP : 1.0f;
    const float* src = W + kt * 8192;

    #pragma unroll
    for (int i = 0; i < 8; i++) {
        int f = i * 1024 + t * 4;
        float4 v = *(const float4*)(src + f);
        int k = f >> 7, n = f & 127;
        _Float16* d = T + k * 136 + n;
        d[0] = (_Float16)(v.x * scale);
        d[1] = (_Float16)(v.y * scale);
        d[2] = (_Float16)(v.z * scale);
        d[3] = (_Float16)(v.w * scale);
    }
    __syncthreads();

    _Float16* dst = wt + m * 131072 + kt * 8192;
    #pragma unroll
    for (int i = 0; i < 4; i++) {
        int p = i * 256 + t;
        int n = p >> 3;
        int c = (p & 7) ^ (n & 7);
        half8 h;
        #pragma unroll
        for (int j = 0; j < 8; j++)
            h[j] = T[(c * 8 + j) * 136 + n];
        *(half8*)(dst + p * 8) = h;
    }
}

// ---------------- fused QKV projection (R0 config: best measured 81us) ----
// grid (256,3); block 256 (4 waves). 64 rows x 128 cols, BK=128 supersteps.
// proj is pinned by the X-read delivery tier (~2.3 TB/s effective for the
// 192MB fp32 X stream); 6 structural variants (R0-R5) all land 81-110us.
// This is the best-measured configuration.
__global__ __launch_bounds__(256) void proj_kernel(
    const float* __restrict__ Xq, const float* __restrict__ Xk,
    const float* __restrict__ Xv, const _Float16* __restrict__ wt,
    _Float16* __restrict__ qs, _Float16* __restrict__ ks_t,
    _Float16* __restrict__ vt_t)
{
    __shared__ float As[64 * 128];        // 32 KB fp32, swizzled chunks/row
    __shared__ _Float16 Bs[2 * 8192];     // 32 KB: two 64-k tiles

    const int t = threadIdx.x;
    const int lane = t & 63;
    const int w = t >> 6;
    const int quad = lane >> 4;
    const int m16 = lane & 15;
    const int yb = blockIdx.y;
    const float* X = (yb == 0) ? Xq : (yb == 1) ? Xk : Xv;
    const _Float16* W = wt + yb * 131072;
    const int m0 = blockIdx.x * 64;

    floatx4 acc[8] = {};
    const int e = m16 & 7;

    for (int s = 0; s < 8; s++) {
        if (s) __syncthreads();
        {   // stage A: 64 rows x 128 floats (2048 16B chunks)
            const float* base = X + (size_t)m0 * 1024 + s * 128;
            #pragma unroll
            for (int i = 0; i < 8; i++) {
                int st = i * 256 + t;
                int row = st >> 5;
                int p = st & 31;
                int c = (p & 24) | ((p & 7) ^ (row & 7));
                __builtin_amdgcn_global_load_lds(
                    (const __attribute__((address_space(1))) unsigned int*)(base + (size_t)row * 1024 + c * 4),
                    (__attribute__((address_space(3))) unsigned int*)(As + st * 4),
                    16, 0, 0);
            }
        }
        {   // stage B: two 64-k tiles = 2048 16B chunks, contiguous source
            const _Float16* src = W + s * 16384;
            #pragma unroll
            for (int i = 0; i < 8; i++) {
                int slot = (w * 8 + i) * 64 + lane;
                __builtin_amdgcn_global_load_lds(
                    (const __attribute__((address_space(1))) unsigned int*)(src + (size_t)slot * 8),
                    (__attribute__((address_space(3))) unsigned int*)(Bs + slot * 8),
                    16, 0, 0);
            }
        }
        __builtin_amdgcn_s_waitcnt(0);
        __syncthreads();

        const float* ap = As + (w * 16 + m16) * 128;
        #pragma unroll
        for (int ks = 0; ks < 2; ks++) {
            const char* bt = (const char*)(Bs + ks * 8192);
            #pragma unroll
            for (int hf2 = 0; hf2 < 2; hf2++) {
                int b16 = ks * 16 + hf2 * 8;
                float4 fa = *(const float4*)(ap + (b16 + ((quad * 2) ^ e)) * 4);
                float4 fb = *(const float4*)(ap + (b16 + ((quad * 2 + 1) ^ e)) * 4);
                half8 af = {(_Float16)fa.x, (_Float16)fa.y, (_Float16)fa.z, (_Float16)fa.w,
                            (_Float16)fb.x, (_Float16)fb.y, (_Float16)fb.z, (_Float16)fb.w};
                int sw = (hf2 * 4 + quad) ^ e;
                #pragma unroll
                for (int nt = 0; nt < 8; nt++) {
                    half8 bf = *(const half8*)(bt + (nt * 16 + m16) * 128 + sw * 16);
                    acc[nt] = __builtin_amdgcn_mfma_f32_16x16x32_f16(af, bf, acc[nt], 0, 0, 0);
                }
            }
        }
    }

    const int b = m0 >> 11;
    const int kt = (m0 & 2047) >> 6;

    if (yb == 0) {
        #pragma unroll
        for (int nt = 0; nt < 8; nt++) {
            #pragma unroll
            for (int r = 0; r < 4; r++) {
                int orow = m0 + w * 16 + quad * 4 + r;
                qs[(size_t)orow * 128 + nt * 16 + m16] = (_Float16)acc[nt][r];
            }
        }
    } else if (yb == 1) {
        // ks tiled: chunk p = row*16 + (d8 ^ (row&7))
        _Float16* tile = ks_t + (size_t)(b * 32 + kt) * 8192;
        #pragma unroll
        for (int nt = 0; nt < 8; nt++) {
            #pragma unroll
            for (int r = 0; r < 4; r++) {
                int row = w * 16 + quad * 4 + r;
                int col = nt * 16 + m16;
                int p = row * 16 + ((col >> 3) ^ (row & 7));
                tile[p * 8 + (col & 7)] = (_Float16)acc[nt][r];
            }
        }
    } else {
        // vt tiled: transpose via LDS, chunk p = dv*8 + (k8 ^ (dv&7))
        __syncthreads();
        _Float16* T = (_Float16*)As;   // 64 x 130 f16
        #pragma unroll
        for (int nt = 0; nt < 8; nt++) {
            #pragma unroll
            for (int r = 0; r < 4; r++)
                T[(w * 16 + quad * 4 + r) * 130 + nt * 16 + m16] = (_Float16)acc[nt][r];
        }
        __syncthreads();
        int dv = t >> 1, hf = t & 1;
        _Float16* tile = vt_t + (size_t)(b * 32 + kt) * 8192;
        #pragma unroll
        for (int j8 = 0; j8 < 4; j8++) {
            int k8 = hf * 4 + j8;
            half8 h;
            #pragma unroll
            for (int j = 0; j < 8; j++)
                h[j] = T[(k8 * 8 + j) * 130 + dv];
            int p = dv * 8 + (k8 ^ (dv & 7));
            *(half8*)(tile + p * 8) = h;
        }
    }
}

// ---------------- flash attention -----------------------------------------
// grid 1D (256*ns); block 256. b = id&7 -> XCD affinity: all 64 blocks
// sharing batch b's K/V land on the same XCD's L2 (round-robin dispatch)
// instead of replicating 8 MB K/V into all 8 L2s.
// Double-buffered async K/V tiles, one barrier per key tile.
// Exact defer-rescale: skip alpha path when rowmax<=m_i (alpha==1 exactly).
// ns==2: key-split halves write unnormalized partials + (m,l).
__global__ __launch_bounds__(256) void attn_kernel(
    const _Float16* __restrict__ qs, const _Float16* __restrict__ ks_t,
    const _Float16* __restrict__ vt_t, const int* __restrict__ mlen,
    float* __restrict__ out, float* __restrict__ part, int ns)
{
    __shared__ _Float16 kbuf[2 * 8192];     // 32 KB
    __shared__ _Float16 vbuf[2 * 8192];     // 32 KB
    __shared__ _Float16 pls[4 * 16 * 72];   // per-wave P

    const int t = threadIdx.x;
    const int lane = t & 63;
    const int w = t >> 6;
    const int quad = lane >> 4;
    const int m16 = lane & 15;
    const int id = blockIdx.x;
    const int b = id & 7;                   // XCD-affine batch mapping
    const int q0 = ((id >> 3) & 31) * 64;
    const int h = id >> 8;
    const int ml = mlen[b];
    const int nkt = (ml + 63) >> 6;
    const int hs = (nkt + ns - 1) / ns;
    const int kb0 = h * hs;
    const int kb1 = min(nkt, (h + 1) * hs);

    half8 aq[4];
    {
        const _Float16* qrow =
            qs + (size_t)(b * 2048 + q0 + w * 16 + m16) * 128 + quad * 8;
        #pragma unroll
        for (int d = 0; d < 4; d++)
            aq[d] = *(const half8*)(qrow + d * 32);
    }

    floatx4 acc[8] = {};
    float m_i[4] = {-3e38f, -3e38f, -3e38f, -3e38f};
    float l_i[4] = {0.f, 0.f, 0.f, 0.f};

    auto stage = [&](int buf, int kt) {
        const _Float16* ksrc = ks_t + (size_t)(b * 32 + kt) * 8192;
        const _Float16* vsrc = vt_t + (size_t)(b * 32 + kt) * 8192;
        #pragma unroll
        for (int i = 0; i < 4; i++) {
            int slot = (w * 4 + i) * 64 + lane;
            __builtin_amdgcn_global_load_lds(
                (const __attribute__((address_space(1))) unsigned int*)(ksrc + (size_t)slot * 8),
                (__attribute__((address_space(3))) unsigned int*)(kbuf + buf * 8192 + slot * 8),
                16, 0, 0);
            __builtin_amdgcn_global_load_lds(
                (const __attribute__((address_space(1))) unsigned int*)(vsrc + (size_t)slot * 8),
                (__attribute__((address_space(3))) unsigned int*)(vbuf + buf * 8192 + slot * 8),
                16, 0, 0);
        }
    };

    if (kb0 < kb1) {
        stage(0, kb0);
        __builtin_amdgcn_s_waitcnt(0);
        __syncthreads();

        for (int kt = kb0; kt < kb1; kt++) {
            const int cur = (kt - kb0) & 1;
            if (kt + 1 < kb1) stage(cur ^ 1, kt + 1);

            const _Float16* kb = kbuf + cur * 8192;
            const _Float16* vb = vbuf + cur * 8192;
            const int k0 = kt * 64;

            // S = (Q/temp) K^T
            floatx4 sacc[4] = {};
            #pragma unroll
            for (int d = 0; d < 4; d++) {
                #pragma unroll
                for (int nt = 0; nt < 4; nt++) {
                    int row = nt * 16 + m16;
                    int p = row * 16 + ((d * 4 + quad) ^ (row & 7));
                    half8 bf = *(const half8*)(kb + p * 8);
                    sacc[nt] = __builtin_amdgcn_mfma_f32_16x16x32_f16(aq[d], bf, sacc[nt], 0, 0, 0);
                }
            }

            // online softmax
            float p4[4][4];
            float rowmax[4], rowsum[4];
            #pragma unroll
            for (int r = 0; r < 4; r++) rowmax[r] = -3e38f;
            #pragma unroll
            for (int nt = 0; nt < 4; nt++) {
                int key = k0 + nt * 16 + m16;
                bool valid = key < ml;
                #pragma unroll
                for (int r = 0; r < 4; r++) {
                    float s = valid ? sacc[nt][r] : -3e38f;
                    p4[nt][r] = s;
                    rowmax[r] = fmaxf(rowmax[r], s);
                }
            }
            #pragma unroll
            for (int mask = 8; mask >= 1; mask >>= 1) {
                #pragma unroll
                for (int r = 0; r < 4; r++)
                    rowmax[r] = fmaxf(rowmax[r], __shfl_xor(rowmax[r], mask, 64));
            }
            // exact defer-rescale: if rowmax<=m_i for all r, alpha==1 exactly
            bool need = (rowmax[0] > m_i[0]) || (rowmax[1] > m_i[1]) ||
                        (rowmax[2] > m_i[2]) || (rowmax[3] > m_i[3]);
            if (need) {
                #pragma unroll
                for (int r = 0; r < 4; r++) {
                    float mnew = fmaxf(m_i[r], rowmax[r]);
                    float alpha = __expf(m_i[r] - mnew);
                    m_i[r] = mnew;
                    l_i[r] *= alpha;
                    #pragma unroll
                    for (int nt = 0; nt < 8; nt++) acc[nt][r] *= alpha;
                }
            }
            #pragma unroll
            for (int r = 0; r < 4; r++) {
                rowsum[r] = 0.f;
                #pragma unroll
                for (int nt = 0; nt < 4; nt++) {
                    float ee = __expf(p4[nt][r] - m_i[r]);
                    p4[nt][r] = ee;
                    rowsum[r] += ee;
                }
            }
            #pragma unroll
            for (int mask = 8; mask >= 1; mask >>= 1) {
                #pragma unroll
                for (int r = 0; r < 4; r++)
                    rowsum[r] += __shfl_xor(rowsum[r], mask, 64);
            }
            #pragma unroll
            for (int r = 0; r < 4; r++) l_i[r] += rowsum[r];

            // P: C-layout -> A-layout, per-wave LDS (no barrier needed)
            _Float16* pw = pls + w * 16 * 72;
            #pragma unroll
            for (int nt = 0; nt < 4; nt++) {
                #pragma unroll
                for (int r = 0; r < 4; r++)
                    pw[(quad * 4 + r) * 72 + nt * 16 + m16] = (_Float16)p4[nt][r];
            }

            // O += P @ V
            #pragma unroll
            for (int kp = 0; kp < 2; kp++) {
                half8 pa = *(const half8*)(pw + m16 * 72 + kp * 32 + quad * 8);
                #pragma unroll
                for (int nt = 0; nt < 8; nt++) {
                    int dv = nt * 16 + m16;
                    int p = dv * 8 + ((kp * 4 + quad) ^ (dv & 7));
                    half8 bf = *(const half8*)(vb + p * 8);
                    acc[nt] = __builtin_amdgcn_mfma_f32_16x16x32_f16(pa, bf, acc[nt], 0, 0, 0);
                }
            }

            __builtin_amdgcn_s_waitcnt(0);
            __syncthreads();
        }
    }

    if (ns == 1) {
        #pragma unroll
        for (int r = 0; r < 4; r++) {
            float inv_l = l_i[r] > 0.f ? 1.0f / l_i[r] : 0.f;
            int orow = b * 2048 + q0 + w * 16 + quad * 4 + r;
            float* dst = out + (size_t)orow * 128;
            #pragma unroll
            for (int nt = 0; nt < 8; nt++)
                __builtin_nontemporal_store(acc[nt][r] * inv_l, &dst[nt * 16 + m16]);
        }
    } else {
        #pragma unroll
        for (int r = 0; r < 4; r++) {
            float* pr = part +
                (size_t)(h * 16384 + b * 2048 + q0 + w * 16 + quad * 4 + r) * 132;
            #pragma unroll
            for (int nt = 0; nt < 8; nt++)
                pr[nt * 16 + m16] = acc[nt][r];
            if (m16 == 0) { pr[128] = m_i[r]; pr[129] = l_i[r]; }
        }
    }
}

// ---------------- merge (ns==2 only) ---------------------------------------
__global__ __launch_bounds__(256) void merge_kernel(
    const float* __restrict__ part, float* __restrict__ out)
{
    int idx = blockIdx.x * 256 + threadIdx.x;   // 2,097,152 elements
    int row = idx >> 7, c = idx & 127;
    const float* p1 = part + (size_t)row * 132;
    const float* p2 = part + (size_t)(16384 + row) * 132;
    float m1 = p1[128], l1 = p1[129];
    float m2 = p2[128], l2 = p2[129];
    float M = fmaxf(m1, m2);
    float s1 = __expf(m1 - M), s2 = __expf(m2 - M);
    float res = (p1[c] * s1 + p2[c] * s2) / (l1 * s1 + l2 * s2);
    __builtin_nontemporal_store(res, &out[idx]);
}

extern "C" void kernel_launch(void* const* d_in, const int* in_sizes, int n_in,
                              void* d_out, int out_size, void* d_ws, size_t ws_size,
                              hipStream_t stream) {
    const float* q   = (const float*)d_in[0];
    const float* k   = (const float*)d_in[1];
    const float* v   = (const float*)d_in[2];
    const int* mlen  = (const int*)d_in[3];
    const float* Wq  = (const float*)d_in[4];
    const float* Wk  = (const float*)d_in[5];
    const float* Wv  = (const float*)d_in[6];
    float* out = (float*)d_out;

    char* ws = (char*)d_ws;
    _Float16* wt   = (_Float16*)(ws + OFF_WT);
    _Float16* qs   = (_Float16*)(ws + OFF_QS);
    _Float16* ks_t = (_Float16*)(ws + OFF_KT);
    _Float16* vt_t = (_Float16*)(ws + OFF_VT);
    float* part    = (float*)(ws + OFF_PART);

    const int ns = (ws_size >= (size_t)OFF_PART + PART_BYTES) ? 2 : 1;

    hipLaunchKernelGGL(wprep_kernel, dim3(16, 3), dim3(256), 0, stream, Wq, Wk, Wv, wt);
    hipLaunchKernelGGL(proj_kernel, dim3(256, 3), dim3(256), 0, stream,
                       q, k, v, wt, qs, ks_t, vt_t);
    hipLaunchKernelGGL(attn_kernel, dim3(256 * ns), dim3(256), 0, stream,
                       qs, ks_t, vt_t, mlen, out, part, ns);
    if (ns == 2)
        hipLaunchKernelGGL(merge_kernel, dim3(8192), dim3(256), 0, stream, part, out);
}

// Round 8
// 260.726 us; speedup vs baseline: 1.1147x; 1.0057x over previous
//
#include <hip/hip_runtime.h>

typedef _Float16 half8 __attribute__((ext_vector_type(8)));
typedef float floatx4 __attribute__((ext_vector_type(4)));

#define INV_TEMP 0.08838834764831845f

// ---------------- workspace layout (bytes) --------------------------------
#define OFF_WT   0                        // 3*128*1024 f16 = 786432 (swizzled)
#define OFF_QS   786432                   // qs linear [16384][128] f16, 4 MiB
#define OFF_KT   (786432 + 4194304)       // ks tiled:  [b][kt][1024 chunks]
#define OFF_VT   (OFF_KT + 4194304)       // vt tiled:  [b][kt][1024 chunks]
#define OFF_PART (OFF_VT + 4194304)       // partials: ns*8*2048*132 fp32
#define PART_BYTES_N(n) ((unsigned long long)(n) * 8 * 2048 * 132 * 4)

// ---------------- weight prep (unchanged) ---------------------------------
// wt: per matrix m, 16 k-tiles of 64k; tile = 1024 chunks of 16B.
// physical chunk p = n*8 + (c ^ (n&7)), logical (n∈[0,128), c∈[0,8)).
__global__ __launch_bounds__(256) void wprep_kernel(
    const float* __restrict__ Wq, const float* __restrict__ Wk,
    const float* __restrict__ Wv, _Float16* __restrict__ wt)
{
    __shared__ _Float16 T[64 * 136];
    const int t = threadIdx.x;
    const int kt = blockIdx.x;
    const int m = blockIdx.y;
    const float* W = (m == 0) ? Wq : (m == 1) ? Wk : Wv;
    const float scale = (m == 0) ? INV_TEMP : 1.0f;
    const float* src = W + kt * 8192;

    #pragma unroll
    for (int i = 0; i < 8; i++) {
        int f = i * 1024 + t * 4;
        float4 v = *(const float4*)(src + f);
        int k = f >> 7, n = f & 127;
        _Float16* d = T + k * 136 + n;
        d[0] = (_Float16)(v.x * scale);
        d[1] = (_Float16)(v.y * scale);
        d[2] = (_Float16)(v.z * scale);
        d[3] = (_Float16)(v.w * scale);
    }
    __syncthreads();

    _Float16* dst = wt + m * 131072 + kt * 8192;
    #pragma unroll
    for (int i = 0; i < 4; i++) {
        int p = i * 256 + t;
        int n = p >> 3;
        int c = (p & 7) ^ (n & 7);
        half8 h;
        #pragma unroll
        for (int j = 0; j < 8; j++)
            h[j] = T[(c * 8 + j) * 136 + n];
        *(half8*)(dst + p * 8) = h;
    }
}

// ---------------- fused QKV projection (R0 config: best measured 76-82us) --
// grid (256,3); block 256 (4 waves). 64 rows x 128 cols, BK=128 supersteps.
// 6 structural variants (R0-R5) all land 77-110us; this is best-measured.
__global__ __launch_bounds__(256) void proj_kernel(
    const float* __restrict__ Xq, const float* __restrict__ Xk,
    const float* __restrict__ Xv, const _Float16* __restrict__ wt,
    _Float16* __restrict__ qs, _Float16* __restrict__ ks_t,
    _Float16* __restrict__ vt_t)
{
    __shared__ float As[64 * 128];        // 32 KB fp32, swizzled chunks/row
    __shared__ _Float16 Bs[2 * 8192];     // 32 KB: two 64-k tiles

    const int t = threadIdx.x;
    const int lane = t & 63;
    const int w = t >> 6;
    const int quad = lane >> 4;
    const int m16 = lane & 15;
    const int yb = blockIdx.y;
    const float* X = (yb == 0) ? Xq : (yb == 1) ? Xk : Xv;
    const _Float16* W = wt + yb * 131072;
    const int m0 = blockIdx.x * 64;

    floatx4 acc[8] = {};
    const int e = m16 & 7;

    for (int s = 0; s < 8; s++) {
        if (s) __syncthreads();
        {   // stage A: 64 rows x 128 floats (2048 16B chunks)
            const float* base = X + (size_t)m0 * 1024 + s * 128;
            #pragma unroll
            for (int i = 0; i < 8; i++) {
                int st = i * 256 + t;
                int row = st >> 5;
                int p = st & 31;
                int c = (p & 24) | ((p & 7) ^ (row & 7));
                __builtin_amdgcn_global_load_lds(
                    (const __attribute__((address_space(1))) unsigned int*)(base + (size_t)row * 1024 + c * 4),
                    (__attribute__((address_space(3))) unsigned int*)(As + st * 4),
                    16, 0, 0);
            }
        }
        {   // stage B: two 64-k tiles = 2048 16B chunks, contiguous source
            const _Float16* src = W + s * 16384;
            #pragma unroll
            for (int i = 0; i < 8; i++) {
                int slot = (w * 8 + i) * 64 + lane;
                __builtin_amdgcn_global_load_lds(
                    (const __attribute__((address_space(1))) unsigned int*)(src + (size_t)slot * 8),
                    (__attribute__((address_space(3))) unsigned int*)(Bs + slot * 8),
                    16, 0, 0);
            }
        }
        __builtin_amdgcn_s_waitcnt(0);
        __syncthreads();

        const float* ap = As + (w * 16 + m16) * 128;
        #pragma unroll
        for (int ks = 0; ks < 2; ks++) {
            const char* bt = (const char*)(Bs + ks * 8192);
            #pragma unroll
            for (int hf2 = 0; hf2 < 2; hf2++) {
                int b16 = ks * 16 + hf2 * 8;
                float4 fa = *(const float4*)(ap + (b16 + ((quad * 2) ^ e)) * 4);
                float4 fb = *(const float4*)(ap + (b16 + ((quad * 2 + 1) ^ e)) * 4);
                half8 af = {(_Float16)fa.x, (_Float16)fa.y, (_Float16)fa.z, (_Float16)fa.w,
                            (_Float16)fb.x, (_Float16)fb.y, (_Float16)fb.z, (_Float16)fb.w};
                int sw = (hf2 * 4 + quad) ^ e;
                #pragma unroll
                for (int nt = 0; nt < 8; nt++) {
                    half8 bf = *(const half8*)(bt + (nt * 16 + m16) * 128 + sw * 16);
                    acc[nt] = __builtin_amdgcn_mfma_f32_16x16x32_f16(af, bf, acc[nt], 0, 0, 0);
                }
            }
        }
    }

    const int b = m0 >> 11;
    const int kt = (m0 & 2047) >> 6;

    if (yb == 0) {
        #pragma unroll
        for (int nt = 0; nt < 8; nt++) {
            #pragma unroll
            for (int r = 0; r < 4; r++) {
                int orow = m0 + w * 16 + quad * 4 + r;
                qs[(size_t)orow * 128 + nt * 16 + m16] = (_Float16)acc[nt][r];
            }
        }
    } else if (yb == 1) {
        // ks tiled: chunk p = row*16 + (d8 ^ (row&7))
        _Float16* tile = ks_t + (size_t)(b * 32 + kt) * 8192;
        #pragma unroll
        for (int nt = 0; nt < 8; nt++) {
            #pragma unroll
            for (int r = 0; r < 4; r++) {
                int row = w * 16 + quad * 4 + r;
                int col = nt * 16 + m16;
                int p = row * 16 + ((col >> 3) ^ (row & 7));
                tile[p * 8 + (col & 7)] = (_Float16)acc[nt][r];
            }
        }
    } else {
        // vt tiled: transpose via LDS, chunk p = dv*8 + (k8 ^ (dv&7))
        __syncthreads();
        _Float16* T = (_Float16*)As;   // 64 x 130 f16
        #pragma unroll
        for (int nt = 0; nt < 8; nt++) {
            #pragma unroll
            for (int r = 0; r < 4; r++)
                T[(w * 16 + quad * 4 + r) * 130 + nt * 16 + m16] = (_Float16)acc[nt][r];
        }
        __syncthreads();
        int dv = t >> 1, hf = t & 1;
        _Float16* tile = vt_t + (size_t)(b * 32 + kt) * 8192;
        #pragma unroll
        for (int j8 = 0; j8 < 4; j8++) {
            int k8 = hf * 4 + j8;
            half8 h;
            #pragma unroll
            for (int j = 0; j < 8; j++)
                h[j] = T[(k8 * 8 + j) * 130 + dv];
            int p = dv * 8 + (k8 ^ (dv & 7));
            *(half8*)(tile + p * 8) = h;
        }
    }
}

// ---------------- flash attention -----------------------------------------
// grid 1D (256*ns); block 256. Decode: q-tile fastest (spreads every batch
// across all XCDs -- R7's b=id&7 batch->XCD pinning concentrated the
// max-mlen batch on one XCD; reverted). ns-way key-split shortens the
// serial per-block tile chain (latency-bound): halves write unnormalized
// partials + (m,l); merge combines.
// Exact defer-rescale: skip alpha path when rowmax<=m_i (alpha==1 exactly).
__global__ __launch_bounds__(256) void attn_kernel(
    const _Float16* __restrict__ qs, const _Float16* __restrict__ ks_t,
    const _Float16* __restrict__ vt_t, const int* __restrict__ mlen,
    float* __restrict__ out, float* __restrict__ part, int ns)
{
    __shared__ _Float16 kbuf[2 * 8192];     // 32 KB
    __shared__ _Float16 vbuf[2 * 8192];     // 32 KB
    __shared__ _Float16 pls[4 * 16 * 72];   // per-wave P

    const int t = threadIdx.x;
    const int lane = t & 63;
    const int w = t >> 6;
    const int quad = lane >> 4;
    const int m16 = lane & 15;
    const int id = blockIdx.x;
    const int q0 = (id & 31) * 64;          // fastest: q-tile (XCD round-robin)
    const int b = (id >> 5) & 7;
    const int h = id >> 8;                  // key-split index, 0..ns-1
    const int ml = mlen[b];
    const int nkt = (ml + 63) >> 6;
    const int hs = (nkt + ns - 1) / ns;
    const int kb0 = min(nkt, h * hs);
    const int kb1 = min(nkt, (h + 1) * hs);

    half8 aq[4];
    {
        const _Float16* qrow =
            qs + (size_t)(b * 2048 + q0 + w * 16 + m16) * 128 + quad * 8;
        #pragma unroll
        for (int d = 0; d < 4; d++)
            aq[d] = *(const half8*)(qrow + d * 32);
    }

    floatx4 acc[8] = {};
    float m_i[4] = {-3e38f, -3e38f, -3e38f, -3e38f};
    float l_i[4] = {0.f, 0.f, 0.f, 0.f};

    auto stage = [&](int buf, int kt) {
        const _Float16* ksrc = ks_t + (size_t)(b * 32 + kt) * 8192;
        const _Float16* vsrc = vt_t + (size_t)(b * 32 + kt) * 8192;
        #pragma unroll
        for (int i = 0; i < 4; i++) {
            int slot = (w * 4 + i) * 64 + lane;
            __builtin_amdgcn_global_load_lds(
                (const __attribute__((address_space(1))) unsigned int*)(ksrc + (size_t)slot * 8),
                (__attribute__((address_space(3))) unsigned int*)(kbuf + buf * 8192 + slot * 8),
                16, 0, 0);
            __builtin_amdgcn_global_load_lds(
                (const __attribute__((address_space(1))) unsigned int*)(vsrc + (size_t)slot * 8),
                (__attribute__((address_space(3))) unsigned int*)(vbuf + buf * 8192 + slot * 8),
                16, 0, 0);
        }
    };

    if (kb0 < kb1) {
        stage(0, kb0);
        __builtin_amdgcn_s_waitcnt(0);
        __syncthreads();

        for (int kt = kb0; kt < kb1; kt++) {
            const int cur = (kt - kb0) & 1;
            if (kt + 1 < kb1) stage(cur ^ 1, kt + 1);

            const _Float16* kb = kbuf + cur * 8192;
            const _Float16* vb = vbuf + cur * 8192;
            const int k0 = kt * 64;

            // S = (Q/temp) K^T
            floatx4 sacc[4] = {};
            #pragma unroll
            for (int d = 0; d < 4; d++) {
                #pragma unroll
                for (int nt = 0; nt < 4; nt++) {
                    int row = nt * 16 + m16;
                    int p = row * 16 + ((d * 4 + quad) ^ (row & 7));
                    half8 bf = *(const half8*)(kb + p * 8);
                    sacc[nt] = __builtin_amdgcn_mfma_f32_16x16x32_f16(aq[d], bf, sacc[nt], 0, 0, 0);
                }
            }

            // online softmax
            float p4[4][4];
            float rowmax[4], rowsum[4];
            #pragma unroll
            for (int r = 0; r < 4; r++) rowmax[r] = -3e38f;
            #pragma unroll
            for (int nt = 0; nt < 4; nt++) {
                int key = k0 + nt * 16 + m16;
                bool valid = key < ml;
                #pragma unroll
                for (int r = 0; r < 4; r++) {
                    float s = valid ? sacc[nt][r] : -3e38f;
                    p4[nt][r] = s;
                    rowmax[r] = fmaxf(rowmax[r], s);
                }
            }
            #pragma unroll
            for (int mask = 8; mask >= 1; mask >>= 1) {
                #pragma unroll
                for (int r = 0; r < 4; r++)
                    rowmax[r] = fmaxf(rowmax[r], __shfl_xor(rowmax[r], mask, 64));
            }
            // exact defer-rescale: if rowmax<=m_i for all r, alpha==1 exactly
            bool need = (rowmax[0] > m_i[0]) || (rowmax[1] > m_i[1]) ||
                        (rowmax[2] > m_i[2]) || (rowmax[3] > m_i[3]);
            if (need) {
                #pragma unroll
                for (int r = 0; r < 4; r++) {
                    float mnew = fmaxf(m_i[r], rowmax[r]);
                    float alpha = __expf(m_i[r] - mnew);
                    m_i[r] = mnew;
                    l_i[r] *= alpha;
                    #pragma unroll
                    for (int nt = 0; nt < 8; nt++) acc[nt][r] *= alpha;
                }
            }
            #pragma unroll
            for (int r = 0; r < 4; r++) {
                rowsum[r] = 0.f;
                #pragma unroll
                for (int nt = 0; nt < 4; nt++) {
                    float ee = __expf(p4[nt][r] - m_i[r]);
                    p4[nt][r] = ee;
                    rowsum[r] += ee;
                }
            }
            #pragma unroll
            for (int mask = 8; mask >= 1; mask >>= 1) {
                #pragma unroll
                for (int r = 0; r < 4; r++)
                    rowsum[r] += __shfl_xor(rowsum[r], mask, 64);
            }
            #pragma unroll
            for (int r = 0; r < 4; r++) l_i[r] += rowsum[r];

            // P: C-layout -> A-layout, per-wave LDS (no barrier needed)
            _Float16* pw = pls + w * 16 * 72;
            #pragma unroll
            for (int nt = 0; nt < 4; nt++) {
                #pragma unroll
                for (int r = 0; r < 4; r++)
                    pw[(quad * 4 + r) * 72 + nt * 16 + m16] = (_Float16)p4[nt][r];
            }

            // O += P @ V
            #pragma unroll
            for (int kp = 0; kp < 2; kp++) {
                half8 pa = *(const half8*)(pw + m16 * 72 + kp * 32 + quad * 8);
                #pragma unroll
                for (int nt = 0; nt < 8; nt++) {
                    int dv = nt * 16 + m16;
                    int p = dv * 8 + ((kp * 4 + quad) ^ (dv & 7));
                    half8 bf = *(const half8*)(vb + p * 8);
                    acc[nt] = __builtin_amdgcn_mfma_f32_16x16x32_f16(pa, bf, acc[nt], 0, 0, 0);
                }
            }

            __builtin_amdgcn_s_waitcnt(0);
            __syncthreads();
        }
    }

    if (ns == 1) {
        #pragma unroll
        for (int r = 0; r < 4; r++) {
            float inv_l = l_i[r] > 0.f ? 1.0f / l_i[r] : 0.f;
            int orow = b * 2048 + q0 + w * 16 + quad * 4 + r;
            float* dst = out + (size_t)orow * 128;
            #pragma unroll
            for (int nt = 0; nt < 8; nt++)
                __builtin_nontemporal_store(acc[nt][r] * inv_l, &dst[nt * 16 + m16]);
        }
    } else {
        #pragma unroll
        for (int r = 0; r < 4; r++) {
            float* pr = part +
                (size_t)(h * 16384 + b * 2048 + q0 + w * 16 + quad * 4 + r) * 132;
            #pragma unroll
            for (int nt = 0; nt < 8; nt++)
                pr[nt * 16 + m16] = acc[nt][r];
            if (m16 == 0) { pr[128] = m_i[r]; pr[129] = l_i[r]; }
        }
    }
}

// ---------------- merge (ns>=2) --------------------------------------------
__global__ __launch_bounds__(256) void merge_kernel(
    const float* __restrict__ part, float* __restrict__ out, int ns)
{
    int idx = blockIdx.x * 256 + threadIdx.x;   // 2,097,152 elements
    int row = idx >> 7, c = idx & 127;
    float M = -3e38f;
    for (int j = 0; j < ns; j++)
        M = fmaxf(M, part[((size_t)(j * 16384 + row)) * 132 + 128]);
    float num = 0.f, den = 0.f;
    for (int j = 0; j < ns; j++) {
        const float* pr = part + ((size_t)(j * 16384 + row)) * 132;
        float s = __expf(pr[128] - M);
        num += pr[c] * s;
        den += pr[129] * s;
    }
    __builtin_nontemporal_store(num / den, &out[idx]);
}

extern "C" void kernel_launch(void* const* d_in, const int* in_sizes, int n_in,
                              void* d_out, int out_size, void* d_ws, size_t ws_size,
                              hipStream_t stream) {
    const float* q   = (const float*)d_in[0];
    const float* k   = (const float*)d_in[1];
    const float* v   = (const float*)d_in[2];
    const int* mlen  = (const int*)d_in[3];
    const float* Wq  = (const float*)d_in[4];
    const float* Wk  = (const float*)d_in[5];
    const float* Wv  = (const float*)d_in[6];
    float* out = (float*)d_out;

    char* ws = (char*)d_ws;
    _Float16* wt   = (_Float16*)(ws + OFF_WT);
    _Float16* qs   = (_Float16*)(ws + OFF_QS);
    _Float16* ks_t = (_Float16*)(ws + OFF_KT);
    _Float16* vt_t = (_Float16*)(ws + OFF_VT);
    float* part    = (float*)(ws + OFF_PART);

    int ns = 1;
    if (ws_size >= (size_t)OFF_PART + PART_BYTES_N(4)) ns = 4;
    else if (ws_size >= (size_t)OFF_PART + PART_BYTES_N(2)) ns = 2;

    hipLaunchKernelGGL(wprep_kernel, dim3(16, 3), dim3(256), 0, stream, Wq, Wk, Wv, wt);
    hipLaunchKernelGGL(proj_kernel, dim3(256, 3), dim3(256), 0, stream,
                       q, k, v, wt, qs, ks_t, vt_t);
    hipLaunchKernelGGL(attn_kernel, dim3(256 * ns), dim3(256), 0, stream,
                       qs, ks_t, vt_t, mlen, out, part, ns);
    if (ns >= 2)
        hipLaunchKernelGGL(merge_kernel, dim3(8192), dim3(256), 0, stream, part, out, ns);
}